// Round 13
// baseline (57.546 us; speedup 1.0000x reference)
//
#include <hip/hip_runtime.h>
#include <math.h>

// IN_C=3, DIM=256, OUT_C=256, N_PIECES=20, BATCH=16, SET_N=128

#if __has_builtin(__builtin_amdgcn_exp2f)
#define EXP2F(x) __builtin_amdgcn_exp2f(x)
#else
#define EXP2F(x) exp2f(x)
#endif

#define LOG2E 1.4426950408889634f

__device__ __forceinline__ float pool_weight(const float* __restrict__ pw, int j)
{
    float ratio = (float)j / 127.0f;
    float idx_f = 20.0f * ratio;
    int idx = (int)idx_f;
    float frac = idx_f - (float)idx;
    int idx2 = idx + 1 > 20 ? 20 : idx + 1;
    return (1.0f - frac) * pw[idx] + frac * pw[idx2];
}

// ---------------------------------------------------------------------------
// K1: conv1+conv2+fspool, 1024 blocks x 512 thr (8 waves), 4 rows/block.
// R12 structure with bank-clean kq-partial reduce:
//   PartS[kq][r][col] (float) -- writes at bank=col (2-way, free),
//   reads at bank=i (2-way, free). Replaces R12's 8-way-conflicted float4.
// ---------------------------------------------------------------------------
__global__ __launch_bounds__(512, 8) void conv_pool_kernel(
    const float* __restrict__ x,   const float* __restrict__ w1,
    const float* __restrict__ b1,  const float* __restrict__ W2,
    const float* __restrict__ b2,  const float* __restrict__ pool_w,
    float* __restrict__ pooled)
{
    __shared__ float4 w1p[256];          // (w1[k,0..2], b1[k])        4 KB
    __shared__ float4 AstT[32];          // (A[r0..3][k]) per step-k   0.5 KB
    __shared__ float2 Bsp2[16][132];     // (h_{2t}, h_{2t+1})[n]      16.5 KB
    __shared__ float  PartS[4][4][128];  // kq-partials [kq][r][col]   8 KB
    __shared__ float  ss[4][128];        // s values                   2 KB
    __shared__ float  bb[4][128];        // B*log2e                    2 KB
    __shared__ float  partial[8];

    int tid = threadIdx.x;
    int blk = blockIdx.x;
    int b   = blk >> 6;                  // batch 0..15
    int c0  = (blk & 63) << 2;           // 4-row channel group

    // conv1-staging role
    int k2 = tid >> 5;                   // kk-pair 0..15
    int n0 = (tid & 31) * 4;             // n quad
    // GEMM role
    int col = tid & 127;
    int kq  = tid >> 7;                  // k-quarter 0..3
    // fspool role
    int wid = tid >> 6, l = tid & 63;
    int r   = wid & 3,  h = wid >> 2;
    int i   = h * 64 + l;

    if (tid < 256)
        w1p[tid] = make_float4(w1[tid*3], w1[tid*3+1], w1[tid*3+2], b1[tid]);
    const float* xb = x + b * 384;
    float4 xc0 = *(const float4*)(xb + n0);
    float4 xc1 = *(const float4*)(xb + 128 + n0);
    float4 xc2 = *(const float4*)(xb + 256 + n0);
    __syncthreads();

    float ac0 = 0.f, ac1 = 0.f, ac2 = 0.f, ac3 = 0.f;

    for (int k0 = 0; k0 < 256; k0 += 32) {
        if (tid < 32) {
            int k = k0 + tid;
            AstT[tid] = make_float4(W2[(c0+0)*256 + k], W2[(c0+1)*256 + k],
                                    W2[(c0+2)*256 + k], W2[(c0+3)*256 + k]);
        }
        {   // conv1: kk = 2*k2, 2*k2+1 for n0..n0+3, packed as kk-pairs
            float4 wv0 = w1p[k0 + 2*k2];
            float4 wv1 = w1p[k0 + 2*k2 + 1];
            float h00 = fmaxf(fmaf(wv0.x,xc0.x, fmaf(wv0.y,xc1.x, fmaf(wv0.z,xc2.x, wv0.w))), 0.f);
            float h01 = fmaxf(fmaf(wv0.x,xc0.y, fmaf(wv0.y,xc1.y, fmaf(wv0.z,xc2.y, wv0.w))), 0.f);
            float h02 = fmaxf(fmaf(wv0.x,xc0.z, fmaf(wv0.y,xc1.z, fmaf(wv0.z,xc2.z, wv0.w))), 0.f);
            float h03 = fmaxf(fmaf(wv0.x,xc0.w, fmaf(wv0.y,xc1.w, fmaf(wv0.z,xc2.w, wv0.w))), 0.f);
            float h10 = fmaxf(fmaf(wv1.x,xc0.x, fmaf(wv1.y,xc1.x, fmaf(wv1.z,xc2.x, wv1.w))), 0.f);
            float h11 = fmaxf(fmaf(wv1.x,xc0.y, fmaf(wv1.y,xc1.y, fmaf(wv1.z,xc2.y, wv1.w))), 0.f);
            float h12 = fmaxf(fmaf(wv1.x,xc0.z, fmaf(wv1.y,xc1.z, fmaf(wv1.z,xc2.z, wv1.w))), 0.f);
            float h13 = fmaxf(fmaf(wv1.x,xc0.w, fmaf(wv1.y,xc1.w, fmaf(wv1.z,xc2.w, wv1.w))), 0.f);
            *(float4*)&Bsp2[k2][n0]     = make_float4(h00, h10, h01, h11);
            *(float4*)&Bsp2[k2][n0 + 2] = make_float4(h02, h12, h03, h13);
        }
        __syncthreads();
        #pragma unroll
        for (int p = 0; p < 4; p++) {
            int t = 4*p + kq;
            float2 bv = Bsp2[t][col];
            float4 a0 = AstT[2*t];
            float4 a1 = AstT[2*t + 1];
            ac0 = fmaf(a0.x, bv.x, ac0); ac0 = fmaf(a1.x, bv.y, ac0);
            ac1 = fmaf(a0.y, bv.x, ac1); ac1 = fmaf(a1.y, bv.y, ac1);
            ac2 = fmaf(a0.z, bv.x, ac2); ac2 = fmaf(a1.z, bv.y, ac2);
            ac3 = fmaf(a0.w, bv.x, ac3); ac3 = fmaf(a1.w, bv.y, ac3);
        }
        __syncthreads();
    }

    // ---- kq-partial reduce (bank-clean) -> ss[r][i] ----
    PartS[kq][0][col] = ac0;
    PartS[kq][1][col] = ac1;
    PartS[kq][2][col] = ac2;
    PartS[kq][3][col] = ac3;
    __syncthreads();
    float s_own = ((PartS[0][r][i] + PartS[1][r][i]) +
                   (PartS[2][r][i] + PartS[3][r][i])) + b2[c0 + r];
    ss[r][i] = s_own;
    __syncthreads();

    // ---- fspool: lane owns i = j for row r ----
    float sa0=0.f, sa1=0.f, sa2=0.f, sa3=0.f;
    #pragma unroll 8
    for (int j = 0; j < 128; j += 4) {
        float4 s4 = *(const float4*)&ss[r][j];
        sa0 += fabsf(s_own - s4.x); sa1 += fabsf(s_own - s4.y);
        sa2 += fabsf(s_own - s4.z); sa3 += fabsf(s_own - s4.w);
    }
    bb[r][i] = ((sa0+sa1)+(sa2+sa3)) * LOG2E;
    __syncthreads();

    float scal = (float)(127 - 2*i) * LOG2E;
    float m0=-1e30f, m1=-1e30f, m2=-1e30f, m3=-1e30f;
    #pragma unroll 8
    for (int k = 0; k < 128; k += 4) {
        float4 s4 = *(const float4*)&ss[r][k];
        float4 b4 = *(const float4*)&bb[r][k];
        m0 = fmaxf(m0, fmaf(s4.x, scal, -b4.x));
        m1 = fmaxf(m1, fmaf(s4.y, scal, -b4.y));
        m2 = fmaxf(m2, fmaf(s4.z, scal, -b4.z));
        m3 = fmaxf(m3, fmaf(s4.w, scal, -b4.w));
    }
    float m = fmaxf(fmaxf(m0, m1), fmaxf(m2, m3));

    float se0=0.f, se1=0.f, se2=0.f, se3=0.f;
    float sd0=0.f, sd1=0.f, sd2=0.f, sd3=0.f;
    #pragma unroll 8
    for (int k = 0; k < 128; k += 4) {
        float4 s4 = *(const float4*)&ss[r][k];
        float4 b4 = *(const float4*)&bb[r][k];
        float e0 = EXP2F(fmaf(s4.x, scal, -b4.x) - m);
        float e1 = EXP2F(fmaf(s4.y, scal, -b4.y) - m);
        float e2 = EXP2F(fmaf(s4.z, scal, -b4.z) - m);
        float e3 = EXP2F(fmaf(s4.w, scal, -b4.w) - m);
        se0 += e0; sd0 = fmaf(e0, s4.x, sd0);
        se1 += e1; sd1 = fmaf(e1, s4.y, sd1);
        se2 += e2; sd2 = fmaf(e2, s4.z, sd2);
        se3 += e3; sd3 = fmaf(e3, s4.w, sd3);
    }
    float xs = ((sd0+sd1)+(sd2+sd3)) / ((se0+se1)+(se2+se3));

    float part = xs * pool_weight(pool_w + (c0 + r) * 21, i);
    #pragma unroll
    for (int off = 32; off > 0; off >>= 1)
        part += __shfl_xor(part, off);
    if (l == 0) partial[wid] = part;
    __syncthreads();
    if (tid < 4)
        pooled[b * 256 + c0 + tid] = partial[tid] + partial[tid + 4];
}

// ---------------------------------------------------------------------------
// K2: MLP tail. 16 blocks x 512 thr (unchanged).
// ---------------------------------------------------------------------------
__device__ __forceinline__ void dense512(
    const float* __restrict__ W, const float* __restrict__ Bv,
    const float* in_lds, float* out_lds, int tid, bool do_relu)
{
    int o = tid >> 1, p = tid & 1;
    const float* wr = W + o * 256 + p * 128;
    const float* ir = in_lds + p * 128;
    float acc = 0.f;
    #pragma unroll
    for (int k = 0; k < 128; k += 4) {
        float4 wv = *(const float4*)(wr + k);
        float4 iv = *(const float4*)(ir + k);
        acc = fmaf(wv.x, iv.x, acc); acc = fmaf(wv.y, iv.y, acc);
        acc = fmaf(wv.z, iv.z, acc); acc = fmaf(wv.w, iv.w, acc);
    }
    acc += __shfl_xor(acc, 1);
    if (p == 0) {
        acc += Bv[o];
        out_lds[o] = do_relu ? fmaxf(acc, 0.f) : acc;
    }
}

__global__ __launch_bounds__(512) void tail_kernel(
    const float* __restrict__ pooled,
    const float* __restrict__ L1w, const float* __restrict__ L1b,
    const float* __restrict__ L2w, const float* __restrict__ L2b,
    const float* __restrict__ C1w, const float* __restrict__ C1b,
    const float* __restrict__ C2w, const float* __restrict__ C2b,
    float* __restrict__ out)
{
    __shared__ float za[256], zb[256];
    int bt = blockIdx.x, tid = threadIdx.x;
    if (tid < 256) za[tid] = pooled[bt * 256 + tid];
    __syncthreads();
    dense512(L1w, L1b, za, zb, tid, true);
    __syncthreads();
    dense512(L2w, L2b, zb, za, tid, false);
    __syncthreads();
    dense512(C1w, C1b, za, zb, tid, true);
    __syncthreads();
    if (tid < 320) {   // cls2: 10 outputs x 32 lanes, 8 k each
        int o = tid >> 5, kb = tid & 31;
        const float* wr = C2w + o * 256 + kb * 8;
        const float* ir = zb + kb * 8;
        float4 w0 = *(const float4*)(wr);
        float4 w1v = *(const float4*)(wr + 4);
        float4 i0 = *(const float4*)(ir);
        float4 i1 = *(const float4*)(ir + 4);
        float p = fmaf(w0.x,i0.x, fmaf(w0.y,i0.y, fmaf(w0.z,i0.z,
                  fmaf(w0.w,i0.w, fmaf(w1v.x,i1.x, fmaf(w1v.y,i1.y,
                  fmaf(w1v.z,i1.z, w1v.w*i1.w)))))));
        #pragma unroll
        for (int off = 16; off > 0; off >>= 1)
            p += __shfl_xor(p, off, 32);
        if (kb == 0) out[bt * 10 + o] = p + C2b[o];
    }
}

// ---------------------------------------------------------------------------
extern "C" void kernel_launch(void* const* d_in, const int* in_sizes, int n_in,
                              void* d_out, int out_size, void* d_ws, size_t ws_size,
                              hipStream_t stream)
{
    (void)in_sizes; (void)n_in; (void)out_size; (void)ws_size;
    const float* x       = (const float*)d_in[0];
    const float* conv1_w = (const float*)d_in[1];
    const float* conv1_b = (const float*)d_in[2];
    const float* conv2_w = (const float*)d_in[3];
    const float* conv2_b = (const float*)d_in[4];
    const float* pool_w  = (const float*)d_in[5];
    const float* lin1_w  = (const float*)d_in[6];
    const float* lin1_b  = (const float*)d_in[7];
    const float* lin2_w  = (const float*)d_in[8];
    const float* lin2_b  = (const float*)d_in[9];
    const float* cls1_w  = (const float*)d_in[10];
    const float* cls1_b  = (const float*)d_in[11];
    const float* cls2_w  = (const float*)d_in[12];
    const float* cls2_b  = (const float*)d_in[13];
    float* out = (float*)d_out;

    float* pooled = (float*)d_ws;        // 4096 floats

    conv_pool_kernel<<<1024, 512, 0, stream>>>(
        x, conv1_w, conv1_b, conv2_w, conv2_b, pool_w, pooled);
    tail_kernel<<<16, 512, 0, stream>>>(pooled,
        lin1_w, lin1_b, lin2_w, lin2_b, cls1_w, cls1_b, cls2_w, cls2_b, out);
}